// Round 3
// baseline (320.216 us; speedup 1.0000x reference)
//
#include <hip/hip_runtime.h>
#include <cstdint>
#include <cstddef>
#include <cfloat>

// Problem constants (match reference)
static constexpr int BATCH = 32;
static constexpr int KJ    = 17;   // heat channels (joints)
static constexpr int LL    = 19;   // limbs
static constexpr int HH    = 160;
static constexpr int WW    = 160;
static constexpr int PPK   = 30;   // top-k peaks
static constexpr int SS    = 10;   // samples along limb
static constexpr int HW    = HH * WW;
static constexpr int CGW   = WW / 4;        // 40 float4 cells per row

// strip-split peak scan
static constexpr int NSTR  = 4;             // strips per channel
static constexpr int SROWS = HH / NSTR;     // 40 rows per strip
static constexpr int SCAP  = 2048;          // candidate capacity per strip (expected ~640)
static constexpr size_t WS_NEED = (size_t)BATCH * KJ * 128 * sizeof(unsigned long long);

// conn staging
static constexpr int HROWS = 80;            // half-plane rows
static constexpr int HCNT  = HROWS * WW;    // 12800 floats = 51.2 KB

__constant__ int d_ska[LL] = {15,13,16,14,11,5,6,5,5,6,7,8,1,0,0,1,2,3,4};
__constant__ int d_skb[LL] = {13,11,14,12,12,11,12,6,7,8,9,10,2,1,2,3,4,5,6};
// t = linspace(0,1,10) in f32 (verified identical to f32(s/9.0))
__constant__ float d_ts[SS] = {
    0.0f,
    (float)(1.0/9.0), (float)(2.0/9.0), (float)(3.0/9.0),
    (float)(4.0/9.0), (float)(5.0/9.0), (float)(6.0/9.0),
    (float)(7.0/9.0), (float)(8.0/9.0),
    1.0f
};

__device__ __forceinline__ float max3f(float a, float b, float c) {
    return fmaxf(fmaxf(a, b), c);
}
__device__ __forceinline__ unsigned long long umax64(unsigned long long a, unsigned long long b) {
    return a > b ? a : b;
}

// ---------------------------------------------------------------------------
// Kernel 1a: strip scan. One block per (ch, strip); finds strip-local top-30
// candidate keys and writes them to ws[ch*128 + strip*30 + r].
// Key = (float_bits << 32) | (0xFFFFFFFF - idx)  -> max = (value, lowest idx).
// ---------------------------------------------------------------------------
__global__ __launch_bounds__(256) void peaks_scan(const float* __restrict__ heat,
                                                  unsigned long long* __restrict__ ws)
{
    const int blk   = blockIdx.x;           // ch*4 + strip
    const int ch    = blk >> 2;
    const int strip = blk & 3;
    const int y0    = strip * SROWS;
    const float* hp = heat + (size_t)ch * HW;

    __shared__ unsigned long long keys[SCAP];
    __shared__ unsigned long long sel4[4 * PPK];
    __shared__ int cnt;

    const int tid  = threadIdx.x;
    const int lane = tid & 63;
    const int wave = tid >> 6;
    const unsigned long long ltmask = ((unsigned long long)1 << lane) - 1ull;

    if (tid == 0) cnt = 0;
    __syncthreads();

    // ---- branchless scan of strip rows [y0, y0+40) ----
    const int cells = SROWS * CGW;          // 1600 float4 cells
    for (int c = tid; c < cells; c += 256) {
        int ly = c / CGW;
        int cg = c - ly * CGW;
        int y  = y0 + ly;
        int x0 = cg * 4;
        int yu = (y > 0) ? y - 1 : 0;
        int yd = (y < HH - 1) ? y + 1 : HH - 1;

        const float* rc = hp + y  * WW + x0;
        const float* ru = hp + yu * WW + x0;
        const float* rd = hp + yd * WW + x0;

        float4 vc = *(const float4*)rc;
        float4 vu = *(const float4*)ru;
        float4 vd = *(const float4*)rd;
        bool hasL = (x0 > 0);
        bool hasR = (x0 + 4 < WW);
        float lc = hasL ? rc[-1] : -FLT_MAX;
        float lu = hasL ? ru[-1] : -FLT_MAX;
        float ld = hasL ? rd[-1] : -FLT_MAX;
        float rcx = hasR ? rc[4] : -FLT_MAX;
        float rux = hasR ? ru[4] : -FLT_MAX;
        float rdx = hasR ? rd[4] : -FLT_MAX;

        float mu0 = max3f(lu, vu.x, vu.y), mu1 = max3f(vu.x, vu.y, vu.z);
        float mu2 = max3f(vu.y, vu.z, vu.w), mu3 = max3f(vu.z, vu.w, rux);
        float mc0 = max3f(lc, vc.x, vc.y), mc1 = max3f(vc.x, vc.y, vc.z);
        float mc2 = max3f(vc.y, vc.z, vc.w), mc3 = max3f(vc.z, vc.w, rcx);
        float md0 = max3f(ld, vd.x, vd.y), md1 = max3f(vd.x, vd.y, vd.z);
        float md2 = max3f(vd.y, vd.z, vd.w), md3 = max3f(vd.z, vd.w, rdx);

        float nm0 = max3f(mu0, mc0, md0);
        float nm1 = max3f(mu1, mc1, md1);
        float nm2 = max3f(mu2, mc2, md2);
        float nm3 = max3f(mu3, mc3, md3);

        bool pk0 = (vc.x == nm0) && (vc.x > 0.1f);
        bool pk1 = (vc.y == nm1) && (vc.y > 0.1f);
        bool pk2 = (vc.z == nm2) && (vc.z > 0.1f);
        bool pk3 = (vc.w == nm3) && (vc.w > 0.1f);

        unsigned long long b0 = __ballot(pk0);
        unsigned long long b1 = __ballot(pk1);
        unsigned long long b2 = __ballot(pk2);
        unsigned long long b3 = __ballot(pk3);
        int c0 = __popcll(b0), c1 = __popcll(b1), c2 = __popcll(b2), c3 = __popcll(b3);
        int tot = c0 + c1 + c2 + c3;
        int base = 0;
        if (lane == 0 && tot > 0) base = atomicAdd(&cnt, tot);
        base = __shfl(base, 0);

        int idx0 = y * WW + x0;
        if (pk0) {
            int slot = base + __popcll(b0 & ltmask);
            if (slot < SCAP)
                keys[slot] = ((unsigned long long)__float_as_uint(vc.x) << 32)
                           | (unsigned long long)(0xFFFFFFFFu - (unsigned)(idx0 + 0));
        }
        if (pk1) {
            int slot = base + c0 + __popcll(b1 & ltmask);
            if (slot < SCAP)
                keys[slot] = ((unsigned long long)__float_as_uint(vc.y) << 32)
                           | (unsigned long long)(0xFFFFFFFFu - (unsigned)(idx0 + 1));
        }
        if (pk2) {
            int slot = base + c0 + c1 + __popcll(b2 & ltmask);
            if (slot < SCAP)
                keys[slot] = ((unsigned long long)__float_as_uint(vc.z) << 32)
                           | (unsigned long long)(0xFFFFFFFFu - (unsigned)(idx0 + 2));
        }
        if (pk3) {
            int slot = base + c0 + c1 + c2 + __popcll(b3 & ltmask);
            if (slot < SCAP)
                keys[slot] = ((unsigned long long)__float_as_uint(vc.w) << 32)
                           | (unsigned long long)(0xFFFFFFFFu - (unsigned)(idx0 + 3));
        }
    }
    __syncthreads();

    const int n = (cnt < SCAP) ? cnt : SCAP;

    // ---- per-wave top-30 over its 512-key chunk ----
    unsigned long long k[8];
    {
        int base0 = wave * 512 + lane;
        #pragma unroll
        for (int i = 0; i < 8; ++i) {
            int p = base0 + i * 64;
            k[i] = (p < n) ? keys[p] : 0ull;
        }
    }
    for (int r = 0; r < PPK; ++r) {
        unsigned long long best = k[0];
        #pragma unroll
        for (int i = 1; i < 8; ++i) best = umax64(best, k[i]);
        #pragma unroll
        for (int off = 1; off < 64; off <<= 1)
            best = umax64(best, (unsigned long long)__shfl_xor((long long)best, off));
        if (best != 0ull) {
            #pragma unroll
            for (int i = 0; i < 8; ++i)
                if (k[i] == best) k[i] = 0ull;     // keys unique when nonzero
        }
        if (lane == 0) sel4[wave * PPK + r] = best;
    }
    __syncthreads();

    // ---- wave 0 merges 120 -> 30, writes to ws ----
    if (wave == 0) {
        unsigned long long m0 = sel4[lane & 63 < 4 * PPK ? lane : 0];
        m0 = (lane < 4 * PPK) ? sel4[lane] : 0ull;
        unsigned long long m1 = (lane + 64 < 4 * PPK) ? sel4[lane + 64] : 0ull;
        unsigned long long* wsout = ws + (size_t)ch * 128 + strip * PPK;
        for (int r = 0; r < PPK; ++r) {
            unsigned long long best = umax64(m0, m1);
            #pragma unroll
            for (int off = 1; off < 64; off <<= 1)
                best = umax64(best, (unsigned long long)__shfl_xor((long long)best, off));
            if (best != 0ull) {
                if (m0 == best) m0 = 0ull;
                else if (m1 == best) m1 = 0ull;
            }
            if (lane == 0) wsout[r] = best;
        }
    }
}

// ---------------------------------------------------------------------------
// Kernel 1b: merge 4 strip top-30s -> channel top-30, subpixel refine, emit.
// One 64-thread block per channel.
// ---------------------------------------------------------------------------
__global__ __launch_bounds__(64) void peaks_merge(const float* __restrict__ heat,
                                                  const unsigned long long* __restrict__ ws,
                                                  float* __restrict__ out)
{
    const int ch   = blockIdx.x;
    const int lane = threadIdx.x;
    const float* hp = heat + (size_t)ch * HW;
    const unsigned long long* kp = ws + (size_t)ch * 128;

    __shared__ unsigned long long sel[PPK];

    unsigned long long m0 = (lane < 4 * PPK) ? kp[lane] : 0ull;
    unsigned long long m1 = (lane + 64 < 4 * PPK) ? kp[lane + 64] : 0ull;
    for (int r = 0; r < PPK; ++r) {
        unsigned long long best = umax64(m0, m1);
        #pragma unroll
        for (int off = 1; off < 64; off <<= 1)
            best = umax64(best, (unsigned long long)__shfl_xor((long long)best, off));
        if (best != 0ull) {
            if (m0 == best) m0 = 0ull;
            else if (m1 == best) m1 = 0ull;
        }
        if (lane == 0) sel[r] = best;
    }
    __syncthreads();

    if (lane < PPK) {
        unsigned long long g = sel[lane];
        float px = 0.0f, py = 0.0f, sc = 0.0f;
        if (g != 0ull) {
            float v = __uint_as_float((unsigned int)(g >> 32));
            int idx = (int)(0xFFFFFFFFu - (unsigned int)(g & 0xFFFFFFFFull));
            int y = idx / WW;
            int x = idx - y * WW;
            float dx = 0.0f, dy = 0.0f;
            if (x > 0 && x < WW - 1 && y > 0 && y < HH - 1) {
                float r_ = hp[y * WW + x + 1];
                float l_ = hp[y * WW + x - 1];
                float dn = hp[(y + 1) * WW + x];
                float up = hp[(y - 1) * WW + x];
                float dx_raw = 0.5f * (r_ - l_);
                float dy_raw = 0.5f * (dn - up);
                float dxx = __fsub_rn(__fadd_rn(r_, l_), 2.0f * v);
                float dyy = __fsub_rn(__fadd_rn(dn, up), 2.0f * v);
                dx = (fabsf(dxx) > 1e-6f) ? (dx_raw / (-dxx)) : dx_raw;
                dy = (fabsf(dyy) > 1e-6f) ? (dy_raw / (-dyy)) : dy_raw;
            }
            px = __fadd_rn((float)x, dx);
            py = __fadd_rn((float)y, dy);
            sc = v;
        }
        float* o = out + ((size_t)ch * PPK + lane) * 3;
        o[0] = px;
        o[1] = py;
        o[2] = sc;
    }
}

// ---------------------------------------------------------------------------
// Fallback fused peaks kernel (validated round 2) — used if ws too small.
// ---------------------------------------------------------------------------
static constexpr int FCAP = 4096;
__global__ __launch_bounds__(256, 4) void peaks_fused(const float* __restrict__ heat,
                                                      float* __restrict__ out)
{
    const int ch = blockIdx.x;
    const float* hp = heat + (size_t)ch * HW;

    __shared__ unsigned long long keys[FCAP];
    __shared__ unsigned long long sel4[4 * PPK];
    __shared__ unsigned long long sel[PPK];
    __shared__ int cnt;

    const int tid  = threadIdx.x;
    const int lane = tid & 63;
    const int wave = tid >> 6;
    const unsigned long long ltmask = ((unsigned long long)1 << lane) - 1ull;

    if (tid == 0) cnt = 0;
    __syncthreads();

    for (int c = tid; c < HW / 4; c += 256) {
        int y  = c / CGW;
        int cg = c - y * CGW;
        int x0 = cg * 4;
        int yu = (y > 0) ? y - 1 : 0;
        int yd = (y < HH - 1) ? y + 1 : HH - 1;
        const float* rc = hp + y  * WW + x0;
        const float* ru = hp + yu * WW + x0;
        const float* rd = hp + yd * WW + x0;
        float4 vc = *(const float4*)rc;
        float4 vu = *(const float4*)ru;
        float4 vd = *(const float4*)rd;
        bool hasL = (x0 > 0);
        bool hasR = (x0 + 4 < WW);
        float lc = hasL ? rc[-1] : -FLT_MAX;
        float lu = hasL ? ru[-1] : -FLT_MAX;
        float ld = hasL ? rd[-1] : -FLT_MAX;
        float rcx = hasR ? rc[4] : -FLT_MAX;
        float rux = hasR ? ru[4] : -FLT_MAX;
        float rdx = hasR ? rd[4] : -FLT_MAX;
        float mu0 = max3f(lu, vu.x, vu.y), mu1 = max3f(vu.x, vu.y, vu.z);
        float mu2 = max3f(vu.y, vu.z, vu.w), mu3 = max3f(vu.z, vu.w, rux);
        float mc0 = max3f(lc, vc.x, vc.y), mc1 = max3f(vc.x, vc.y, vc.z);
        float mc2 = max3f(vc.y, vc.z, vc.w), mc3 = max3f(vc.z, vc.w, rcx);
        float md0 = max3f(ld, vd.x, vd.y), md1 = max3f(vd.x, vd.y, vd.z);
        float md2 = max3f(vd.y, vd.z, vd.w), md3 = max3f(vd.z, vd.w, rdx);
        float nm0 = max3f(mu0, mc0, md0);
        float nm1 = max3f(mu1, mc1, md1);
        float nm2 = max3f(mu2, mc2, md2);
        float nm3 = max3f(mu3, mc3, md3);
        bool pk0 = (vc.x == nm0) && (vc.x > 0.1f);
        bool pk1 = (vc.y == nm1) && (vc.y > 0.1f);
        bool pk2 = (vc.z == nm2) && (vc.z > 0.1f);
        bool pk3 = (vc.w == nm3) && (vc.w > 0.1f);
        unsigned long long b0 = __ballot(pk0);
        unsigned long long b1 = __ballot(pk1);
        unsigned long long b2 = __ballot(pk2);
        unsigned long long b3 = __ballot(pk3);
        int c0 = __popcll(b0), c1 = __popcll(b1), c2 = __popcll(b2), c3 = __popcll(b3);
        int tot = c0 + c1 + c2 + c3;
        int base = 0;
        if (lane == 0 && tot > 0) base = atomicAdd(&cnt, tot);
        base = __shfl(base, 0);
        int idx0 = y * WW + x0;
        if (pk0) { int s = base + __popcll(b0 & ltmask); if (s < FCAP)
            keys[s] = ((unsigned long long)__float_as_uint(vc.x) << 32) | (unsigned long long)(0xFFFFFFFFu - (unsigned)(idx0 + 0)); }
        if (pk1) { int s = base + c0 + __popcll(b1 & ltmask); if (s < FCAP)
            keys[s] = ((unsigned long long)__float_as_uint(vc.y) << 32) | (unsigned long long)(0xFFFFFFFFu - (unsigned)(idx0 + 1)); }
        if (pk2) { int s = base + c0 + c1 + __popcll(b2 & ltmask); if (s < FCAP)
            keys[s] = ((unsigned long long)__float_as_uint(vc.z) << 32) | (unsigned long long)(0xFFFFFFFFu - (unsigned)(idx0 + 2)); }
        if (pk3) { int s = base + c0 + c1 + c2 + __popcll(b3 & ltmask); if (s < FCAP)
            keys[s] = ((unsigned long long)__float_as_uint(vc.w) << 32) | (unsigned long long)(0xFFFFFFFFu - (unsigned)(idx0 + 3)); }
    }
    __syncthreads();

    const int n = (cnt < FCAP) ? cnt : FCAP;
    unsigned long long k[16];
    {
        int base0 = wave * 1024 + lane;
        #pragma unroll
        for (int i = 0; i < 16; ++i) {
            int p = base0 + i * 64;
            k[i] = (p < n) ? keys[p] : 0ull;
        }
    }
    for (int r = 0; r < PPK; ++r) {
        unsigned long long best = k[0];
        #pragma unroll
        for (int i = 1; i < 16; ++i) best = umax64(best, k[i]);
        #pragma unroll
        for (int off = 1; off < 64; off <<= 1)
            best = umax64(best, (unsigned long long)__shfl_xor((long long)best, off));
        if (best != 0ull) {
            #pragma unroll
            for (int i = 0; i < 16; ++i)
                if (k[i] == best) k[i] = 0ull;
        }
        if (lane == 0) sel4[wave * PPK + r] = best;
    }
    __syncthreads();
    if (wave == 0) {
        unsigned long long m0 = (lane < 4 * PPK) ? sel4[lane] : 0ull;
        unsigned long long m1 = (lane + 64 < 4 * PPK) ? sel4[lane + 64] : 0ull;
        for (int r = 0; r < PPK; ++r) {
            unsigned long long best = umax64(m0, m1);
            #pragma unroll
            for (int off = 1; off < 64; off <<= 1)
                best = umax64(best, (unsigned long long)__shfl_xor((long long)best, off));
            if (best != 0ull) {
                if (m0 == best) m0 = 0ull;
                else if (m1 == best) m1 = 0ull;
            }
            if (lane == 0) sel[r] = best;
        }
    }
    __syncthreads();
    if (tid < PPK) {
        unsigned long long g = sel[tid];
        float px = 0.0f, py = 0.0f, sc = 0.0f;
        if (g != 0ull) {
            float v = __uint_as_float((unsigned int)(g >> 32));
            int idx = (int)(0xFFFFFFFFu - (unsigned int)(g & 0xFFFFFFFFull));
            int y = idx / WW;
            int x = idx - y * WW;
            float dx = 0.0f, dy = 0.0f;
            if (x > 0 && x < WW - 1 && y > 0 && y < HH - 1) {
                float r_ = hp[y * WW + x + 1];
                float l_ = hp[y * WW + x - 1];
                float dn = hp[(y + 1) * WW + x];
                float up = hp[(y - 1) * WW + x];
                float dx_raw = 0.5f * (r_ - l_);
                float dy_raw = 0.5f * (dn - up);
                float dxx = __fsub_rn(__fadd_rn(r_, l_), 2.0f * v);
                float dyy = __fsub_rn(__fadd_rn(dn, up), 2.0f * v);
                dx = (fabsf(dxx) > 1e-6f) ? (dx_raw / (-dxx)) : dx_raw;
                dy = (fabsf(dyy) > 1e-6f) ? (dy_raw / (-dyy)) : dy_raw;
            }
            px = __fadd_rn((float)x, dx);
            py = __fadd_rn((float)y, dy);
            sc = v;
        }
        float* o = out + ((size_t)ch * PPK + tid) * 3;
        o[0] = px;
        o[1] = py;
        o[2] = sc;
    }
}

// ---------------------------------------------------------------------------
// Kernel 2: PAF connection scoring with LDS-staged planes.
// One block per (b,l), 512 threads, thread t handles pairs t and t+512.
// 4 phases: {pafx,pafy} x {rows 0-79, rows 80-159} staged into 51.2 KB LDS.
// ---------------------------------------------------------------------------
__global__ __launch_bounds__(512, 2) void conn_kernel(const float* __restrict__ paf,
                                                      const float* __restrict__ peaks,
                                                      float* __restrict__ conn)
{
    const int bl = blockIdx.x;        // b*19 + l
    const int b  = bl / LL;
    const int l  = bl - b * LL;

    __shared__ float4 plane4[HCNT / 4];   // 12800 floats = 51.2 KB
    __shared__ float As[PPK * 3];
    __shared__ float Bs[PPK * 3];
    float* plane = (float*)plane4;

    const int tid = threadIdx.x;
    {
        const float* pa = peaks + (((size_t)b * KJ) + d_ska[l]) * (PPK * 3);
        const float* pb = peaks + (((size_t)b * KJ) + d_skb[l]) * (PPK * 3);
        if (tid < PPK * 3)            As[tid] = pa[tid];
        else if (tid < 2 * PPK * 3)   Bs[tid - PPK * 3] = pb[tid - PPK * 3];
    }
    __syncthreads();

    // ---- per-pair precompute (indices + geometry) ----
    const int npair = (tid + 512 < PPK * PPK) ? 2 : 1;
    int   lin[2][SS];
    float acc[2][SS];
    float vxp[2], vyp[2], sap[2], sbp[2];

    for (int q = 0; q < npair; ++q) {
        int p = tid + q * 512;
        int i = p / PPK;
        int j = p - i * PPK;
        float ax = As[i * 3 + 0], ay = As[i * 3 + 1], sa = As[i * 3 + 2];
        float bx = Bs[j * 3 + 0], by = Bs[j * 3 + 1], sb = Bs[j * 3 + 2];
        float dxl = __fsub_rn(bx, ax);
        float dyl = __fsub_rn(by, ay);
        float nsq = __fadd_rn(__fmul_rn(dxl, dxl), __fmul_rn(dyl, dyl));
        float nrm = __fadd_rn(sqrtf(nsq), 1e-8f);
        vxp[q] = dxl / nrm;
        vyp[q] = dyl / nrm;
        sap[q] = sa;
        sbp[q] = sb;
        #pragma unroll
        for (int s = 0; s < SS; ++s) {
            float t  = d_ts[s];
            float xs = __fadd_rn(ax, __fmul_rn(t, dxl));
            float ys = __fadd_rn(ay, __fmul_rn(t, dyl));
            float rx = rintf(xs);               // round half to even, matches jnp.round
            float ry = rintf(ys);
            rx = fminf(fmaxf(rx, 0.0f), (float)(WW - 1));
            ry = fminf(fmaxf(ry, 0.0f), (float)(HH - 1));
            lin[q][s] = (int)ry * WW + (int)rx;
        }
    }

    // ---- 4 staging+gather phases ----
    for (int phase = 0; phase < 4; ++phase) {
        const int comp = phase >> 1;          // 0 = pafx, 1 = pafy
        const int half = phase & 1;           // 0 = rows 0-79, 1 = rows 80-159
        const float4* src = (const float4*)(paf + (((size_t)b * (2 * LL)) + 2 * l + comp) * HW
                                                + half * HCNT);
        __syncthreads();                       // previous phase's gathers done
        for (int i = tid; i < HCNT / 4; i += 512)
            plane4[i] = src[i];
        __syncthreads();                       // staging visible

        const int lo = half * HCNT;
        for (int q = 0; q < npair; ++q) {
            #pragma unroll
            for (int s = 0; s < SS; ++s) {
                int lrel = lin[q][s] - lo;
                if ((unsigned)lrel < (unsigned)HCNT) {
                    float v = plane[lrel];
                    if (comp == 0) acc[q][s] = __fmul_rn(v, vxp[q]);
                    else           acc[q][s] = __fadd_rn(acc[q][s], __fmul_rn(v, vyp[q]));
                }
            }
        }
    }

    // ---- fold + emit ----
    for (int q = 0; q < npair; ++q) {
        int p = tid + q * 512;
        int cntc = 0;
        #pragma unroll
        for (int s = 0; s < SS; ++s)
            if (acc[q][s] > 0.05f) ++cntc;
        float s01 = __fadd_rn(acc[q][0], acc[q][1]);
        float s23 = __fadd_rn(acc[q][2], acc[q][3]);
        float s45 = __fadd_rn(acc[q][4], acc[q][5]);
        float s67 = __fadd_rn(acc[q][6], acc[q][7]);
        float sum = __fadd_rn(__fadd_rn(s01, s23), __fadd_rn(s45, s67));
        sum = __fadd_rn(sum, acc[q][8]);
        sum = __fadd_rn(sum, acc[q][9]);
        float mean = sum / 10.0f;
        bool va = sap[q] > 0.1f;
        bool vb = sbp[q] > 0.1f;
        bool cond = (mean > 0.0f) && (cntc >= 9) && va && vb;
        float val = 0.0f;
        if (cond) val = __fadd_rn(mean, __fmul_rn(0.5f, __fadd_rn(sap[q], sbp[q])));
        conn[(size_t)bl * (PPK * PPK) + p] = val;
    }
}

extern "C" void kernel_launch(void* const* d_in, const int* in_sizes, int n_in,
                              void* d_out, int out_size, void* d_ws, size_t ws_size,
                              hipStream_t stream)
{
    const float* heat = (const float*)d_in[0];   // [32,17,160,160]
    const float* paf  = (const float*)d_in[1];   // [32,38,160,160]
    float* out = (float*)d_out;

    float* peaks_out = out;                                   // 32*17*30*3 = 48960
    float* conn_out  = out + (size_t)BATCH * KJ * PPK * 3;    // 32*19*30*30 = 547200

    if (ws_size >= WS_NEED) {
        unsigned long long* ws64 = (unsigned long long*)d_ws;
        hipLaunchKernelGGL(peaks_scan, dim3(BATCH * KJ * NSTR), dim3(256), 0, stream,
                           heat, ws64);
        hipLaunchKernelGGL(peaks_merge, dim3(BATCH * KJ), dim3(64), 0, stream,
                           heat, ws64, peaks_out);
    } else {
        hipLaunchKernelGGL(peaks_fused, dim3(BATCH * KJ), dim3(256), 0, stream,
                           heat, peaks_out);
    }
    hipLaunchKernelGGL(conn_kernel, dim3(BATCH * LL), dim3(512), 0, stream,
                       paf, peaks_out, conn_out);
}